// Round 19
// baseline (84.424 us; speedup 1.0000x reference)
//
#include <hip/hip_runtime.h>
#include <stdint.h>

#define H_HEADS 16
#define ADIM    128
#define SLEN    2048
#define DMODEL  2048

typedef __attribute__((ext_vector_type(8))) short  short8;
typedef __attribute__((ext_vector_type(4))) float  float4v;
typedef __attribute__((ext_vector_type(4))) unsigned short ushort4v;

typedef const __attribute__((address_space(1))) unsigned int gas_u32;
typedef __attribute__((address_space(3))) unsigned int las_u32;

union F4 { float4 v; float a[4]; };
union PU { unsigned u[4]; short8 s; };

__device__ __forceinline__ unsigned short f2bf(float f) {
  union { float f; unsigned u; } v; v.f = f;
  unsigned r = v.u + 0x7FFFu + ((v.u >> 16) & 1u);   // RNE
  return (unsigned short)(r >> 16);
}
__device__ __forceinline__ unsigned cvt_pk_bf16(float lo, float hi) {
  unsigned r;
  asm("v_cvt_pk_bf16_f32 %0, %1, %2" : "=v"(r) : "v"(lo), "v"(hi));
  return r;
}
// after p32+p16 swap: a = [x@r0, x@r2, y@r0, y@r2], b = [x@r1, x@r3, y@r1, y@r3]
__device__ __forceinline__ void xswap(unsigned& a, unsigned& b) {
  asm volatile("v_permlane32_swap_b32 %0, %1" : "+v"(a), "+v"(b));
  asm volatile("v_permlane16_swap_b32 %0, %1" : "+v"(a), "+v"(b));
}
__device__ __forceinline__ float fsin01(float r) { float o; asm("v_sin_f32 %0, %1" : "=v"(o) : "v"(r)); return o; }
__device__ __forceinline__ float fcos01(float r) { float o; asm("v_cos_f32 %0, %1" : "=v"(o) : "v"(r)); return o; }
__device__ __forceinline__ float ffract(float x) { float o; asm("v_fract_f32 %0, %1" : "=v"(o) : "v"(x)); return o; }
__device__ __forceinline__ float hexp2(float x)  { float o; asm("v_exp_f32 %0, %1" : "=v"(o) : "v"(x)); return o; }

#define ROPE_C 0.20762050593045935f    // log2(10000)/64
#define L2I2PI -2.651496129472319f     // log2(1/(2*pi))
#define C2LOG  0.12751879523103988f    // (1/sqrt(128)) * log2(e)
#define Z0     8.0f                    // fixed softmax shift, validated r6-r18

// ---------------- prep_kv: fused single-pass prep (r18-verified shell).
// Blocks [0, kblocks): RoPE(K) -> bf16 [B*H][S][128], chunk ^= (s&7)      (verified r5-r18)
// Blocks [kblocks, +B*1024): V per 32-key tile -> bf16 [bh][tile32][128][32],
//                            chunk = (i>>1)^(d&3)                         (verified r5)
__global__ __launch_bounds__(256) void prep_kv(const float* __restrict__ xk,
                                               const float* __restrict__ xv,
                                               unsigned short* __restrict__ kw,
                                               unsigned short* __restrict__ vw,
                                               int kblocks) {
  int n = blockIdx.x;
  if (n < kblocks) {
    int t = n * 256 + threadIdx.x;
    int i4 = t & 15;
    int h  = (t >> 4) & (H_HEADS - 1);
    int s  = (t >> 8) & (SLEN - 1);
    int b  = t >> 19;
    int i0 = i4 * 4;
    long ib = ((long)(b * SLEN + s)) * DMODEL + h * ADIM;
    F4 x1, x2;
    x1.v = *(const float4*)(xk + ib + i0);
    x2.v = *(const float4*)(xk + ib + i0 + 64);
    ushort4v o1, o2;
    #pragma unroll
    for (int j = 0; j < 4; ++j) {
      float rev = (float)s * exp2f(fmaf(-(float)(i0 + j), ROPE_C, L2I2PI));
      float r = ffract(rev);
      float sn = fsin01(r), cs = fcos01(r);
      o1[j] = f2bf( x1.a[j] * cs + x2.a[j] * sn);
      o2[j] = f2bf(-x1.a[j] * sn + x2.a[j] * cs);
    }
    long row = ((long)((b * H_HEADS + h) * SLEN + s)) * ADIM;
    int swz = s & 7;
    int c1 = ((((i0     ) >> 3) ^ swz) << 3) | (i0 & 7);
    int c2 = ((((i0 + 64) >> 3) ^ swz) << 3) | (i0 & 7);
    *(ushort4v*)(kw + row + c1) = o1;
    *(ushort4v*)(kw + row + c2) = o2;
  } else {
    // ---- prep_v body (r5 verbatim: KVBLK=32 tiles)
    __shared__ float lv[32 * 129];
    int mm = n - kblocks;
    int jt = mm & 63;                 // 32-key tile 0..63
    int bh = mm >> 6;
    int b = bh >> 4, h = bh & (H_HEADS - 1);
    int t = threadIdx.x;
    #pragma unroll
    for (int it = 0; it < 4; ++it) {            // 1024 float4 reads
      int id  = it * 256 + t;
      int row = id >> 5;                        // key 0..31
      int c4  = (id & 31) * 4;
      F4 x;
      x.v = *(const float4*)(xv + ((long)(b * SLEN + jt * 32 + row)) * DMODEL + h * ADIM + c4);
      #pragma unroll
      for (int j = 0; j < 4; ++j) lv[row * 129 + c4 + j] = x.a[j];
    }
    __syncthreads();
    unsigned short* vt = vw + ((long)(bh * 64 + jt)) * 4096;   // [128][32]
    #pragma unroll
    for (int it = 0; it < 4; ++it) {            // 1024 ushort4 writes
      int id = it * 256 + t;
      int d  = id >> 3;                         // 0..127
      int i  = id & 7;                          // keys 4i..4i+3
      ushort4v o;
      #pragma unroll
      for (int j = 0; j < 4; ++j) o[j] = f2bf(lv[(4 * i + j) * 129 + d]);
      int off = d * 32 + ((((i >> 1) ^ (d & 3)) << 3) | ((i & 1) << 2));
      *(ushort4v*)(vt + off) = o;
    }
  }
}

// ---------------- fused causal flash attention — "lean R5"
// 4-wave blocks, wave = 16 q-rows, KVBLK=32, K+V dbuf LDS = 32KB -> 4 blocks/CU (16 waves,
// 4/SIMD). R12 lean math (zero-C QK, fixed-shift SMAX, full K=32 pack, ones-l, unroll x2).
// Grid 1024 = 4/CU; per-CU c-quad {31-k,16+k,15-k,k} sums to 62 -> uniform 132 iters/CU.
__global__ __launch_bounds__(256, 4) void attn_fwd(const float* __restrict__ xq,
                                                   const unsigned short* __restrict__ kw,
                                                   const unsigned short* __restrict__ vw,
                                                   float* __restrict__ out) {
  __shared__ __align__(16) unsigned short kL[2][32 * 128];   // 2 x 8KB
  __shared__ __align__(16) unsigned short vL[2][128 * 32];   // 2 x 8KB

  int n = blockIdx.x;                   // 0..1023
  int rr = n >> 8;                      // round 0..3
  int m8 = n & 255;
  int xcd = m8 & 7, hq = (m8 >> 3) & 3;
  int bh  = xcd * 4 + hq;               // 4 heads per XCD (verified r12 mapping)
  int k   = m8 >> 5;                    // 0..7
  int c   = (rr == 0) ? (31 - k) : (rr == 1) ? (16 + k) : (rr == 2) ? (15 - k) : k;
  int b = bh >> 4, h = bh & (H_HEADS - 1);
  int t = threadIdx.x, l = t & 63, w = t >> 6;
  int lq = l & 15, gq = l >> 4, lq7 = lq & 7, lq3 = lq & 3;
  int basew = c * 64 + w * 16;          // this wave's 16 rows
  int sq = basew + lq;

  // ---- Q: RoPE in-register (verified r5-r18), single subgroup
  short8 qf[4];
  {
    const float* qsrc = xq + ((long)(b * SLEN + sq)) * DMODEL + h * ADIM;
    float q32[4][8];
    #pragma unroll
    for (int cc = 0; cc < 4; ++cc) {
      F4 lo, hi;
      lo.v = *(const float4*)(qsrc + cc * 32 + gq * 8);
      hi.v = *(const float4*)(qsrc + cc * 32 + gq * 8 + 4);
      #pragma unroll
      for (int jj = 0; jj < 4; ++jj) { q32[cc][jj] = lo.a[jj]; q32[cc][jj + 4] = hi.a[jj]; }
    }
    #pragma unroll
    for (int cc = 0; cc < 2; ++cc) {
      #pragma unroll
      for (int jj = 0; jj < 8; ++jj) {
        int a = cc * 32 + gq * 8 + jj;
        float rev = (float)sq * exp2f(fmaf(-(float)a, ROPE_C, L2I2PI));
        float r = ffract(rev);
        float sn = fsin01(r), cs = fcos01(r);
        qf[cc    ][jj] = (short)f2bf( q32[cc][jj] * cs + q32[cc + 2][jj] * sn);
        qf[cc + 2][jj] = (short)f2bf(-q32[cc][jj] * sn + q32[cc + 2][jj] * cs);
      }
    }
  }

  float4v acc[8], lacc;
  #pragma unroll
  for (int i = 0; i < 8; ++i) acc[i] = (float4v){0.f,0.f,0.f,0.f};
  lacc = (float4v){0.f,0.f,0.f,0.f};
  const float4v Z4 = (float4v){0.f,0.f,0.f,0.f};

  PU ones;                              // bf16 1.0 x8 (verified r6-r18)
  ones.u[0] = 0x3F803F80u; ones.u[1] = 0x3F803F80u; ones.u[2] = 0x3F803F80u; ones.u[3] = 0x3F803F80u;

  const unsigned short* kbase = kw + (long)bh * SLEN * ADIM;
  const unsigned short* vbase = vw + (long)bh * 64 * 4096;

  unsigned short* kst[2] = { &kL[0][0], &kL[1][0] };
  unsigned short* vst[2] = { &vL[0][0], &vL[1][0] };
  const unsigned short* klr[2] = { kst[0] + lq * 128, kst[1] + lq * 128 };
  const unsigned short* vlr[2] = { vst[0] + lq * 32 + ((gq ^ lq3) << 3),
                                   vst[1] + lq * 32 + ((gq ^ lq3) << 3) };   // r5-verified
  int koff[4];
  #pragma unroll
  for (int cc = 0; cc < 4; ++cc) koff[cc] = ((cc * 4 + gq) ^ lq7) << 3;

  auto STAGE = [&](unsigned short* kd, unsigned short* vd, int tile) {   // r5 verbatim
    const unsigned short* ks = kbase + (long)tile * 4096;
    const unsigned short* vs = vbase + (long)tile * 4096;
    #pragma unroll
    for (int i = 0; i < 2; ++i) {
      int seg = w * 2 + i;                     // 8 segs of 512 ushorts each
      __builtin_amdgcn_global_load_lds((gas_u32*)(ks + seg * 512 + l * 8),
                                       (las_u32*)&kd[seg * 512], 16, 0, 0);
      __builtin_amdgcn_global_load_lds((gas_u32*)(vs + seg * 512 + l * 8),
                                       (las_u32*)&vd[seg * 512], 16, 0, 0);
    }
  };

  // fixed-shift softmax on 8 scores -> full K=32 A-frag (r4/r5/r15-verified pack) + l
  auto SMAX = [&](float4v (&sv)[2], bool dg, int tj) -> short8 {
    float p[8];
    #pragma unroll
    for (int kb = 0; kb < 2; ++kb) {
      #pragma unroll
      for (int r = 0; r < 4; ++r) {
        float e = fmaf(sv[kb][r], C2LOG, -Z0);
        if (dg && (tj * 32 + kb * 16 + gq * 4 + r > sq)) e = -1e30f;
        p[kb * 4 + r] = hexp2(e);
      }
    }
    unsigned L0 = cvt_pk_bf16(p[0], p[1]);
    unsigned H0 = cvt_pk_bf16(p[2], p[3]);
    unsigned L1 = cvt_pk_bf16(p[4], p[5]);
    unsigned H1 = cvt_pk_bf16(p[6], p[7]);
    xswap(L0, L1);
    xswap(H0, H1);
    PU a;
    a.u[0] = L0; a.u[1] = H0; a.u[2] = L1; a.u[3] = H1;
    lacc = __builtin_amdgcn_mfma_f32_16x16x32_bf16(a.s, ones.s, lacc, 0, 0, 0);
    return a.s;
  };

  int nt = 2 * c + 2;                   // 32-key tiles (even)

  auto ITER = [&](int m, const unsigned short* klrow, const unsigned short* vlrow,
                  unsigned short* kn, unsigned short* vn) {
    if (m + 1 < nt) STAGE(kn, vn, m + 1);
    bool act = (m * 32 <= basew + 15);         // wave-uniform
    if (act) {
      // ---- swapped QK^T (32 keys), zero-C first step
      float4v s[2];
      __builtin_amdgcn_s_setprio(1);
      {
        #pragma unroll
        for (int kb = 0; kb < 2; ++kb) {
          short8 kf = *(const short8*)&klrow[kb * 2048 + koff[0]];
          s[kb] = __builtin_amdgcn_mfma_f32_16x16x32_bf16(kf, qf[0], Z4, 0, 0, 0);
        }
        #pragma unroll
        for (int cc = 1; cc < 4; ++cc) {
          #pragma unroll
          for (int kb = 0; kb < 2; ++kb) {
            short8 kf = *(const short8*)&klrow[kb * 2048 + koff[cc]];
            s[kb] = __builtin_amdgcn_mfma_f32_16x16x32_bf16(kf, qf[cc], s[kb], 0, 0, 0);
          }
        }
      }
      __builtin_amdgcn_s_setprio(0);

      bool dg = (m * 32 + 31 > basew);
      short8 pa = SMAX(s, dg, m);

      // ---- PV (r5-verified addresses)
      __builtin_amdgcn_s_setprio(1);
      #pragma unroll
      for (int db = 0; db < 8; ++db) {
        short8 vb = *(const short8*)&vlrow[db * 512];
        acc[db] = __builtin_amdgcn_mfma_f32_16x16x32_bf16(pa, vb, acc[db], 0, 0, 0);
      }
      __builtin_amdgcn_s_setprio(0);
    }
    asm volatile("s_waitcnt vmcnt(0)" ::: "memory");
    __builtin_amdgcn_s_barrier();
  };

  // ---- prologue
  STAGE(kst[0], vst[0], 0);
  asm volatile("s_waitcnt vmcnt(0)" ::: "memory");
  __builtin_amdgcn_s_barrier();

  // ---- main loop, unrolled x2 with static buffers (nt even)
  for (int m = 0; m < nt; m += 2) {
    ITER(m,     klr[0], vlr[0], kst[1], vst[1]);
    ITER(m + 1, klr[1], vlr[1], kst[0], vst[0]);
  }

  // ---- epilogue: normalize (l complete per wave) and store fp32 (verified layout)
  float linv[4];
  #pragma unroll
  for (int r = 0; r < 4; ++r) linv[r] = 1.0f / lacc[r];
  #pragma unroll
  for (int db = 0; db < 8; ++db)
    #pragma unroll
    for (int r = 0; r < 4; ++r)
      out[((long)(b * SLEN + basew + gq * 4 + r)) * DMODEL + h * ADIM + db * 16 + lq]
        = acc[db][r] * linv[r];
}

extern "C" void kernel_launch(void* const* d_in, const int* in_sizes, int n_in,
                              void* d_out, int out_size, void* d_ws, size_t ws_size,
                              hipStream_t stream) {
  const float* xq = (const float*)d_in[0];
  const float* xk = (const float*)d_in[1];
  const float* xv = (const float*)d_in[2];
  float* outp = (float*)d_out;
  int B = in_sizes[0] / (SLEN * DMODEL);                    // 2
  size_t perT = (size_t)B * H_HEADS * SLEN * ADIM;
  unsigned short* kw = (unsigned short*)d_ws;               // 16.78 MB
  unsigned short* vw = kw + perT;                           // 16.78 MB

  int kblocks = B * 2048;                                   // K-prep blocks
  int vblocks = B * 1024;                                   // V-prep blocks (64 tiles x B*16 heads)
  prep_kv<<<dim3(kblocks + vblocks), 256, 0, stream>>>(xk, xv, kw, vw, kblocks);
  attn_fwd<<<dim3(B * H_HEADS * 32), 256, 0, stream>>>(xq, kw, vw, outp);  // 1024 blocks
}